// Round 1
// baseline (100852.789 us; speedup 1.0000x reference)
//
#include <hip/hip_runtime.h>
#include <hip/hip_bf16.h>
#include <math.h>

// Problem constants
#define BATCH 8
#define SEQ   1024
#define DMODEL 768
#define DEPTH 12
#define NHEAD 12
#define DHEAD 64
#define DFF   3072
#define MROWS (BATCH*SEQ)        // 8192
#define QKVN  (3*DMODEL)         // 2304

// ---------------- LayerNorm: one block per row of 768 ----------------
__global__ __launch_bounds__(256) void ln_kernel(
    const float* __restrict__ in, float* __restrict__ out,
    const float* __restrict__ w, const float* __restrict__ b)
{
    int row = blockIdx.x;
    const float* x = in + (size_t)row * DMODEL;
    int tid = threadIdx.x;

    float v[3];
    float lsum = 0.f, lsq = 0.f;
#pragma unroll
    for (int i = 0; i < 3; ++i) {
        v[i] = x[tid + i * 256];
        lsum += v[i];
        lsq  += v[i] * v[i];
    }
    // wave (64) reduce
#pragma unroll
    for (int off = 32; off > 0; off >>= 1) {
        lsum += __shfl_down(lsum, off);
        lsq  += __shfl_down(lsq,  off);
    }
    __shared__ float red[10];
    int wave = tid >> 6, lane = tid & 63;
    if (lane == 0) { red[wave] = lsum; red[wave + 4] = lsq; }
    __syncthreads();
    if (tid == 0) {
        float s = red[0] + red[1] + red[2] + red[3];
        float q = red[4] + red[5] + red[6] + red[7];
        float mu = s * (1.0f / DMODEL);
        float var = q * (1.0f / DMODEL) - mu * mu;
        red[8] = mu;
        red[9] = rsqrtf(var + 1e-5f);
    }
    __syncthreads();
    float mu = red[8], rs = red[9];
    float* o = out + (size_t)row * DMODEL;
#pragma unroll
    for (int i = 0; i < 3; ++i) {
        int c = tid + i * 256;
        o[c] = (v[i] - mu) * rs * w[c] + b[c];
    }
}

// ---------------- Tiled fp32 GEMM: C = act(A@B + bias) + resid ----------------
// A: [M,K] row-major, B: [K,N] row-major. 64x64 tile, BK=16, 4x4 per thread.
// act: 0 = none, 1 = exact GELU. bias/resid may be null.
#define TS 64
#define KS 16
__global__ __launch_bounds__(256) void gemm_kernel(
    const float* __restrict__ A, const float* __restrict__ B_,
    const float* __restrict__ bias, const float* __restrict__ resid,
    float* __restrict__ C, int M, int N, int K, int act)
{
    __shared__ float As[KS][TS + 1];  // [k][m], +1 pad to kill write conflicts
    __shared__ float Bs[KS][TS];      // [k][n], 2-way read aliasing is free

    int tid = threadIdx.x;
    int tx = tid & 15;     // n-subtile
    int ty = tid >> 4;     // m-subtile
    int m0 = blockIdx.y * TS;
    int n0 = blockIdx.x * TS;

    float acc[4][4] = {};

    for (int k0 = 0; k0 < K; k0 += KS) {
#pragma unroll
        for (int r = 0; r < 4; ++r) {
            int idx = tid + r * 256;
            int mm = idx >> 4;          // /16
            int kk = idx & 15;
            As[kk][mm] = A[(size_t)(m0 + mm) * K + (k0 + kk)];
        }
#pragma unroll
        for (int r = 0; r < 4; ++r) {
            int idx = tid + r * 256;
            int kk = idx >> 6;          // /64
            int nn = idx & 63;
            Bs[kk][nn] = B_[(size_t)(k0 + kk) * N + (n0 + nn)];
        }
        __syncthreads();
#pragma unroll
        for (int k = 0; k < KS; ++k) {
            float a[4], b[4];
#pragma unroll
            for (int i = 0; i < 4; ++i) a[i] = As[k][ty * 4 + i];
#pragma unroll
            for (int j = 0; j < 4; ++j) b[j] = Bs[k][tx * 4 + j];
#pragma unroll
            for (int i = 0; i < 4; ++i)
#pragma unroll
                for (int j = 0; j < 4; ++j)
                    acc[i][j] += a[i] * b[j];
        }
        __syncthreads();
    }

#pragma unroll
    for (int i = 0; i < 4; ++i) {
        int m = m0 + ty * 4 + i;
#pragma unroll
        for (int j = 0; j < 4; ++j) {
            int n = n0 + tx * 4 + j;
            float val = acc[i][j];
            if (bias) val += bias[n];
            if (act == 1) val = 0.5f * val * (1.0f + erff(val * 0.70710678118f));
            if (resid) val += resid[(size_t)m * N + n];
            C[(size_t)m * N + n] = val;
        }
    }
}

// ---------------- Attention: one block per (batch, head, q_row) ----------------
// qkv: [MROWS, 2304]; q cols [h*64 .. ), k cols [768 + h*64 ..), v cols [1536 + h*64 ..)
// out: [MROWS, 768] at col h*64+d
__global__ __launch_bounds__(256) void attn_kernel(
    const float* __restrict__ qkv, float* __restrict__ out)
{
    int qi    = blockIdx.x;   // 0..1023
    int head  = blockIdx.y;   // 0..11
    int batch = blockIdx.z;   // 0..7
    int row = batch * SEQ + qi;

    const float* qrow  = qkv + (size_t)row * QKVN + head * DHEAD;
    const float* Kbase = qkv + (size_t)batch * SEQ * QKVN + DMODEL + head * DHEAD;
    const float* Vbase = Kbase + DMODEL;

    __shared__ float qs[DHEAD];
    __shared__ float sc[SEQ];
    __shared__ float rr[8];
    __shared__ float part[4][DHEAD];

    int tid = threadIdx.x;
    if (tid < DHEAD) qs[tid] = qrow[tid];
    __syncthreads();

    const float scale = 0.125f;  // 1/sqrt(64)
    // scores
#pragma unroll
    for (int r = 0; r < 4; ++r) {
        int j = tid + r * 256;
        const float* krow = Kbase + (size_t)j * QKVN;
        float dot = 0.f;
#pragma unroll
        for (int d = 0; d < DHEAD; ++d) dot += qs[d] * krow[d];
        sc[j] = dot * scale;
    }
    __syncthreads();

    // max
    float m = -1e30f;
#pragma unroll
    for (int r = 0; r < 4; ++r) m = fmaxf(m, sc[tid + r * 256]);
#pragma unroll
    for (int off = 32; off > 0; off >>= 1) m = fmaxf(m, __shfl_down(m, off));
    int wave = tid >> 6, lane = tid & 63;
    if (lane == 0) rr[wave] = m;
    __syncthreads();
    if (tid == 0) rr[4] = fmaxf(fmaxf(rr[0], rr[1]), fmaxf(rr[2], rr[3]));
    __syncthreads();
    m = rr[4];

    // exp + sum
    float lsum = 0.f;
#pragma unroll
    for (int r = 0; r < 4; ++r) {
        int j = tid + r * 256;
        float p = expf(sc[j] - m);
        sc[j] = p;
        lsum += p;
    }
#pragma unroll
    for (int off = 32; off > 0; off >>= 1) lsum += __shfl_down(lsum, off);
    __syncthreads();            // everyone done reading rr[4]
    if (lane == 0) rr[wave] = lsum;
    __syncthreads();
    if (tid == 0) rr[5] = rr[0] + rr[1] + rr[2] + rr[3];
    __syncthreads();
    float denom = rr[5];

    // PV: thread t handles d = t&63 over j-range group g = t>>6
    int d = tid & 63;
    int g = tid >> 6;
    float po = 0.f;
    const float* vp = Vbase + (size_t)(g * 256) * QKVN + d;
    for (int j = 0; j < 256; ++j) po += sc[g * 256 + j] * vp[(size_t)j * QKVN];
    part[g][d] = po;
    __syncthreads();
    if (tid < DHEAD) {
        float o = (part[0][tid] + part[1][tid] + part[2][tid] + part[3][tid]) / denom;
        out[(size_t)row * DMODEL + head * DHEAD + tid] = o;
    }
}

// ---------------- Launcher ----------------
extern "C" void kernel_launch(void* const* d_in, const int* in_sizes, int n_in,
                              void* d_out, int out_size, void* d_ws, size_t ws_size,
                              hipStream_t stream)
{
    const float* x      = (const float*)d_in[0];
    const float* ln1_w  = (const float*)d_in[1];
    const float* ln1_b  = (const float*)d_in[2];
    const float* w_qkv  = (const float*)d_in[3];
    const float* w_o    = (const float*)d_in[4];
    const float* b_o    = (const float*)d_in[5];
    const float* ln2_w  = (const float*)d_in[6];
    const float* ln2_b  = (const float*)d_in[7];
    const float* w1     = (const float*)d_in[8];
    const float* b1     = (const float*)d_in[9];
    const float* w2     = (const float*)d_in[10];
    const float* b2     = (const float*)d_in[11];
    const float* lnf_w  = (const float*)d_in[12];
    const float* lnf_b  = (const float*)d_in[13];
    float* out = (float*)d_out;

    float* ws   = (float*)d_ws;
    float* xbuf = ws;                                   // MROWS*DMODEL
    float* h    = xbuf + (size_t)MROWS * DMODEL;        // MROWS*DMODEL (also attn_out)
    float* qkv  = h    + (size_t)MROWS * DMODEL;        // MROWS*QKVN
    float* ffn1 = qkv  + (size_t)MROWS * QKVN;          // MROWS*DFF

    // x -> xbuf
    hipMemcpyAsync(xbuf, x, (size_t)MROWS * DMODEL * sizeof(float),
                   hipMemcpyDeviceToDevice, stream);

    for (int l = 0; l < DEPTH; ++l) {
        const float* l1w = ln1_w + (size_t)l * DMODEL;
        const float* l1b = ln1_b + (size_t)l * DMODEL;
        const float* wq  = w_qkv + (size_t)l * DMODEL * QKVN;
        const float* wo  = w_o   + (size_t)l * DMODEL * DMODEL;
        const float* bo  = b_o   + (size_t)l * DMODEL;
        const float* l2w = ln2_w + (size_t)l * DMODEL;
        const float* l2b = ln2_b + (size_t)l * DMODEL;
        const float* W1  = w1    + (size_t)l * DMODEL * DFF;
        const float* B1  = b1    + (size_t)l * DFF;
        const float* W2  = w2    + (size_t)l * DFF * DMODEL;
        const float* B2  = b2    + (size_t)l * DMODEL;

        // h = LN1(x)
        ln_kernel<<<MROWS, 256, 0, stream>>>(xbuf, h, l1w, l1b);
        // qkv = h @ w_qkv
        gemm_kernel<<<dim3(QKVN / TS, MROWS / TS), 256, 0, stream>>>(
            h, wq, nullptr, nullptr, qkv, MROWS, QKVN, DMODEL, 0);
        // attn -> h (reuse)
        attn_kernel<<<dim3(SEQ, NHEAD, BATCH), 256, 0, stream>>>(qkv, h);
        // x = h @ w_o + b_o + x
        gemm_kernel<<<dim3(DMODEL / TS, MROWS / TS), 256, 0, stream>>>(
            h, wo, bo, xbuf, xbuf, MROWS, DMODEL, DMODEL, 0);
        // h = LN2(x)
        ln_kernel<<<MROWS, 256, 0, stream>>>(xbuf, h, l2w, l2b);
        // ffn1 = gelu(h @ w1 + b1)
        gemm_kernel<<<dim3(DFF / TS, MROWS / TS), 256, 0, stream>>>(
            h, W1, B1, nullptr, ffn1, MROWS, DFF, DMODEL, 1);
        // x = ffn1 @ w2 + b2 + x
        gemm_kernel<<<dim3(DMODEL / TS, MROWS / TS), 256, 0, stream>>>(
            ffn1, W2, B2, xbuf, xbuf, MROWS, DMODEL, DFF, 0);
    }

    // out = LN_f(x)
    ln_kernel<<<MROWS, 256, 0, stream>>>(xbuf, out, lnf_w, lnf_b);
}

// Round 2
// 35203.870 us; speedup vs baseline: 2.8648x; 2.8648x over previous
//
#include <hip/hip_runtime.h>
#include <hip/hip_bf16.h>
#include <math.h>

// Problem constants
#define BATCH 8
#define SEQ   1024
#define DMODEL 768
#define DEPTH 12
#define NHEAD 12
#define DHEAD 64
#define DFF   3072
#define MROWS (BATCH*SEQ)        // 8192
#define QKVN  (3*DMODEL)         // 2304

// ---------------- LayerNorm: one block per row of 768 ----------------
__global__ __launch_bounds__(256) void ln_kernel(
    const float* __restrict__ in, float* __restrict__ out,
    const float* __restrict__ w, const float* __restrict__ b)
{
    int row = blockIdx.x;
    const float* x = in + (size_t)row * DMODEL;
    int tid = threadIdx.x;

    float v[3];
    float lsum = 0.f, lsq = 0.f;
#pragma unroll
    for (int i = 0; i < 3; ++i) {
        v[i] = x[tid + i * 256];
        lsum += v[i];
        lsq  += v[i] * v[i];
    }
#pragma unroll
    for (int off = 32; off > 0; off >>= 1) {
        lsum += __shfl_down(lsum, off);
        lsq  += __shfl_down(lsq,  off);
    }
    __shared__ float red[10];
    int wave = tid >> 6, lane = tid & 63;
    if (lane == 0) { red[wave] = lsum; red[wave + 4] = lsq; }
    __syncthreads();
    if (tid == 0) {
        float s = red[0] + red[1] + red[2] + red[3];
        float q = red[4] + red[5] + red[6] + red[7];
        float mu = s * (1.0f / DMODEL);
        float var = q * (1.0f / DMODEL) - mu * mu;
        red[8] = mu;
        red[9] = rsqrtf(var + 1e-5f);
    }
    __syncthreads();
    float mu = red[8], rs = red[9];
    float* o = out + (size_t)row * DMODEL;
#pragma unroll
    for (int i = 0; i < 3; ++i) {
        int c = tid + i * 256;
        o[c] = (v[i] - mu) * rs * w[c] + b[c];
    }
}

// ---------------- Tiled fp32 GEMM: C = act(A@B + bias) + resid ----------------
#define TS 64
#define KS 16
__global__ __launch_bounds__(256) void gemm_kernel(
    const float* __restrict__ A, const float* __restrict__ B_,
    const float* __restrict__ bias, const float* __restrict__ resid,
    float* __restrict__ C, int M, int N, int K, int act)
{
    __shared__ float As[KS][TS + 1];
    __shared__ float Bs[KS][TS];

    int tid = threadIdx.x;
    int tx = tid & 15;
    int ty = tid >> 4;
    int m0 = blockIdx.y * TS;
    int n0 = blockIdx.x * TS;

    float acc[4][4] = {};

    for (int k0 = 0; k0 < K; k0 += KS) {
#pragma unroll
        for (int r = 0; r < 4; ++r) {
            int idx = tid + r * 256;
            int mm = idx >> 4;
            int kk = idx & 15;
            As[kk][mm] = A[(size_t)(m0 + mm) * K + (k0 + kk)];
        }
#pragma unroll
        for (int r = 0; r < 4; ++r) {
            int idx = tid + r * 256;
            int kk = idx >> 6;
            int nn = idx & 63;
            Bs[kk][nn] = B_[(size_t)(k0 + kk) * N + (n0 + nn)];
        }
        __syncthreads();
#pragma unroll
        for (int k = 0; k < KS; ++k) {
            float a[4], b[4];
#pragma unroll
            for (int i = 0; i < 4; ++i) a[i] = As[k][ty * 4 + i];
#pragma unroll
            for (int j = 0; j < 4; ++j) b[j] = Bs[k][tx * 4 + j];
#pragma unroll
            for (int i = 0; i < 4; ++i)
#pragma unroll
                for (int j = 0; j < 4; ++j)
                    acc[i][j] += a[i] * b[j];
        }
        __syncthreads();
    }

#pragma unroll
    for (int i = 0; i < 4; ++i) {
        int m = m0 + ty * 4 + i;
#pragma unroll
        for (int j = 0; j < 4; ++j) {
            int n = n0 + tx * 4 + j;
            float val = acc[i][j];
            if (bias) val += bias[n];
            if (act == 1) val = 0.5f * val * (1.0f + erff(val * 0.70710678118f));
            if (resid) val += resid[(size_t)m * N + n];
            C[(size_t)m * N + n] = val;
        }
    }
}

// ---------------- Flash attention: one block per (b, h, 64-query tile) ----------------
// LDS tiles stride 68 floats: rows 16B-aligned, worst bank aliasing 2-way (free).
#define PADF 68
__global__ __launch_bounds__(256) void fattn_kernel(
    const float* __restrict__ qkv, float* __restrict__ out)
{
    __shared__ float Qs[64][PADF];
    __shared__ float Ks[64][PADF];   // reused as P after S phase
    __shared__ float Vs[64][PADF];

    int qt = blockIdx.x;   // 0..15
    int h  = blockIdx.y;   // 0..11
    int b  = blockIdx.z;   // 0..7
    int tid = threadIdx.x;
    int tx = tid & 15;     // k-col / d-col subtile
    int ty = tid >> 4;     // q-row subtile (also load row group)
    int c4 = tid & 15;     // float4 slot within a 64-col row

    const float* Qbase = qkv + ((size_t)(b * SEQ + qt * 64)) * QKVN + h * DHEAD;
    const float* Kbase = qkv + ((size_t)(b * SEQ)) * QKVN + DMODEL + h * DHEAD;
    const float* Vbase = Kbase + DMODEL;

    // Load Q tile, pre-scaled by 1/sqrt(64)
#pragma unroll
    for (int rr = 0; rr < 4; ++rr) {
        int r = ty + 16 * rr;
        float4 q4 = *(const float4*)(Qbase + (size_t)r * QKVN + c4 * 4);
        q4.x *= 0.125f; q4.y *= 0.125f; q4.z *= 0.125f; q4.w *= 0.125f;
        *(float4*)&Qs[r][c4 * 4] = q4;
    }

    float m_i[4], l_i[4], o[4][4];
#pragma unroll
    for (int i = 0; i < 4; ++i) {
        m_i[i] = -1e30f; l_i[i] = 0.f;
#pragma unroll
        for (int j = 0; j < 4; ++j) o[i][j] = 0.f;
    }

    for (int kt = 0; kt < 16; ++kt) {
        // Prefetch K/V tile into registers (overlaps prior PV phase)
        float4 kreg[4], vreg[4];
#pragma unroll
        for (int rr = 0; rr < 4; ++rr) {
            int r = kt * 64 + ty + 16 * rr;
            kreg[rr] = *(const float4*)(Kbase + (size_t)r * QKVN + c4 * 4);
            vreg[rr] = *(const float4*)(Vbase + (size_t)r * QKVN + c4 * 4);
        }
        __syncthreads();   // prior PV reads of Ks(P)/Vs complete
#pragma unroll
        for (int rr = 0; rr < 4; ++rr) {
            int r = ty + 16 * rr;
            *(float4*)&Ks[r][c4 * 4] = kreg[rr];
            *(float4*)&Vs[r][c4 * 4] = vreg[rr];
        }
        __syncthreads();   // tiles ready

        // S = Q @ K^T (per thread: 4 q-rows x 4 k-cols)
        float s[4][4] = {};
#pragma unroll
        for (int d0 = 0; d0 < 64; d0 += 4) {
            float4 a4[4], b4[4];
#pragma unroll
            for (int i = 0; i < 4; ++i) a4[i] = *(const float4*)&Qs[ty * 4 + i][d0];
#pragma unroll
            for (int j = 0; j < 4; ++j) b4[j] = *(const float4*)&Ks[tx * 4 + j][d0];
#pragma unroll
            for (int i = 0; i < 4; ++i)
#pragma unroll
                for (int j = 0; j < 4; ++j)
                    s[i][j] += a4[i].x * b4[j].x + a4[i].y * b4[j].y
                             + a4[i].z * b4[j].z + a4[i].w * b4[j].w;
        }

        // Online softmax update (row stats across the 16-lane tx group)
#pragma unroll
        for (int i = 0; i < 4; ++i) {
            float rm = fmaxf(fmaxf(s[i][0], s[i][1]), fmaxf(s[i][2], s[i][3]));
#pragma unroll
            for (int off = 8; off > 0; off >>= 1) rm = fmaxf(rm, __shfl_xor(rm, off));
            float mnew = fmaxf(m_i[i], rm);
            float alpha = __expf(m_i[i] - mnew);
            float sum = 0.f;
#pragma unroll
            for (int j = 0; j < 4; ++j) {
                s[i][j] = __expf(s[i][j] - mnew);
                sum += s[i][j];
            }
#pragma unroll
            for (int off = 8; off > 0; off >>= 1) sum += __shfl_xor(sum, off);
            l_i[i] = l_i[i] * alpha + sum;
            m_i[i] = mnew;
#pragma unroll
            for (int j = 0; j < 4; ++j) o[i][j] *= alpha;
        }

        __syncthreads();   // S reads of Ks done; safe to overwrite with P
#pragma unroll
        for (int i = 0; i < 4; ++i)
            *(float4*)&Ks[ty * 4 + i][tx * 4] = make_float4(s[i][0], s[i][1], s[i][2], s[i][3]);
        __syncthreads();   // P ready

        // O += P @ V
#pragma unroll
        for (int k0 = 0; k0 < 64; k0 += 4) {
            float p4[4][4], v4[4][4];
#pragma unroll
            for (int i = 0; i < 4; ++i)
                *(float4*)p4[i] = *(const float4*)&Ks[ty * 4 + i][k0];
#pragma unroll
            for (int c = 0; c < 4; ++c)
                *(float4*)v4[c] = *(const float4*)&Vs[k0 + c][tx * 4];
#pragma unroll
            for (int i = 0; i < 4; ++i)
#pragma unroll
                for (int j = 0; j < 4; ++j)
                    o[i][j] += p4[i][0] * v4[0][j] + p4[i][1] * v4[1][j]
                             + p4[i][2] * v4[2][j] + p4[i][3] * v4[3][j];
        }
    }

    // Epilogue: normalize and store
#pragma unroll
    for (int i = 0; i < 4; ++i) {
        float inv = 1.0f / l_i[i];
        int row = b * SEQ + qt * 64 + ty * 4 + i;
        float4 r = make_float4(o[i][0] * inv, o[i][1] * inv, o[i][2] * inv, o[i][3] * inv);
        *(float4*)(out + (size_t)row * DMODEL + h * DHEAD + tx * 4) = r;
    }
}

// ---------------- Launcher ----------------
extern "C" void kernel_launch(void* const* d_in, const int* in_sizes, int n_in,
                              void* d_out, int out_size, void* d_ws, size_t ws_size,
                              hipStream_t stream)
{
    const float* x      = (const float*)d_in[0];
    const float* ln1_w  = (const float*)d_in[1];
    const float* ln1_b  = (const float*)d_in[2];
    const float* w_qkv  = (const float*)d_in[3];
    const float* w_o    = (const float*)d_in[4];
    const float* b_o    = (const float*)d_in[5];
    const float* ln2_w  = (const float*)d_in[6];
    const float* ln2_b  = (const float*)d_in[7];
    const float* w1     = (const float*)d_in[8];
    const float* b1     = (const float*)d_in[9];
    const float* w2     = (const float*)d_in[10];
    const float* b2     = (const float*)d_in[11];
    const float* lnf_w  = (const float*)d_in[12];
    const float* lnf_b  = (const float*)d_in[13];
    float* out = (float*)d_out;

    float* ws   = (float*)d_ws;
    float* xbuf = ws;                                   // MROWS*DMODEL
    float* h    = xbuf + (size_t)MROWS * DMODEL;        // MROWS*DMODEL (also attn_out)
    float* qkv  = h    + (size_t)MROWS * DMODEL;        // MROWS*QKVN
    float* ffn1 = qkv  + (size_t)MROWS * QKVN;          // MROWS*DFF

    hipMemcpyAsync(xbuf, x, (size_t)MROWS * DMODEL * sizeof(float),
                   hipMemcpyDeviceToDevice, stream);

    for (int l = 0; l < DEPTH; ++l) {
        const float* l1w = ln1_w + (size_t)l * DMODEL;
        const float* l1b = ln1_b + (size_t)l * DMODEL;
        const float* wq  = w_qkv + (size_t)l * DMODEL * QKVN;
        const float* wo  = w_o   + (size_t)l * DMODEL * DMODEL;
        const float* bo  = b_o   + (size_t)l * DMODEL;
        const float* l2w = ln2_w + (size_t)l * DMODEL;
        const float* l2b = ln2_b + (size_t)l * DMODEL;
        const float* W1  = w1    + (size_t)l * DMODEL * DFF;
        const float* B1  = b1    + (size_t)l * DFF;
        const float* W2  = w2    + (size_t)l * DFF * DMODEL;
        const float* B2  = b2    + (size_t)l * DMODEL;

        ln_kernel<<<MROWS, 256, 0, stream>>>(xbuf, h, l1w, l1b);
        gemm_kernel<<<dim3(QKVN / TS, MROWS / TS), 256, 0, stream>>>(
            h, wq, nullptr, nullptr, qkv, MROWS, QKVN, DMODEL, 0);
        fattn_kernel<<<dim3(SEQ / 64, NHEAD, BATCH), 256, 0, stream>>>(qkv, h);
        gemm_kernel<<<dim3(DMODEL / TS, MROWS / TS), 256, 0, stream>>>(
            h, wo, bo, xbuf, xbuf, MROWS, DMODEL, DMODEL, 0);
        ln_kernel<<<MROWS, 256, 0, stream>>>(xbuf, h, l2w, l2b);
        gemm_kernel<<<dim3(DFF / TS, MROWS / TS), 256, 0, stream>>>(
            h, W1, B1, nullptr, ffn1, MROWS, DFF, DMODEL, 1);
        gemm_kernel<<<dim3(DMODEL / TS, MROWS / TS), 256, 0, stream>>>(
            ffn1, W2, B2, xbuf, xbuf, MROWS, DMODEL, DFF, 0);
    }

    ln_kernel<<<MROWS, 256, 0, stream>>>(xbuf, out, lnf_w, lnf_b);
}

// Round 3
// 13060.318 us; speedup vs baseline: 7.7221x; 2.6955x over previous
//
#include <hip/hip_runtime.h>
#include <hip/hip_bf16.h>
#include <math.h>

#define BATCH 8
#define SEQ   1024
#define DMODEL 768
#define DEPTH 12
#define NHEAD 12
#define DHEAD 64
#define DFF   3072
#define MROWS (BATCH*SEQ)        // 8192
#define QKVN  (3*DMODEL)         // 2304

typedef __attribute__((ext_vector_type(8))) short bf16x8;
typedef __attribute__((ext_vector_type(4))) float f32x4;

__device__ __forceinline__ float bfbits(unsigned int u) {
    union { unsigned int i; float f; } c; c.i = u; return c.f;
}
__device__ __forceinline__ void unpack8(uint4 raw, float* f) {
    const unsigned int* u = (const unsigned int*)&raw;
#pragma unroll
    for (int i = 0; i < 4; ++i) {
        f[2*i]   = bfbits(u[i] << 16);
        f[2*i+1] = bfbits(u[i] & 0xffff0000u);
    }
}
__device__ __forceinline__ void gld16(const void* g, void* l) {
    __builtin_amdgcn_global_load_lds(
        (const __attribute__((address_space(1))) void*)g,
        (__attribute__((address_space(3))) void*)l, 16, 0, 0);
}

// ---------------- LayerNorm: fp32 in, bf16 or fp32 out ----------------
template<int BF16OUT>
__global__ __launch_bounds__(256) void ln_kernel(
    const float* __restrict__ in, void* __restrict__ outp,
    const float* __restrict__ w, const float* __restrict__ b)
{
    int row = blockIdx.x;
    const float* x = in + (size_t)row * DMODEL;
    int tid = threadIdx.x;

    float v[3];
    float lsum = 0.f, lsq = 0.f;
#pragma unroll
    for (int i = 0; i < 3; ++i) {
        v[i] = x[tid + i * 256];
        lsum += v[i];
        lsq  += v[i] * v[i];
    }
#pragma unroll
    for (int off = 32; off > 0; off >>= 1) {
        lsum += __shfl_down(lsum, off);
        lsq  += __shfl_down(lsq,  off);
    }
    __shared__ float red[10];
    int wave = tid >> 6, lane = tid & 63;
    if (lane == 0) { red[wave] = lsum; red[wave + 4] = lsq; }
    __syncthreads();
    if (tid == 0) {
        float s = red[0] + red[1] + red[2] + red[3];
        float q = red[4] + red[5] + red[6] + red[7];
        float mu = s * (1.0f / DMODEL);
        float var = q * (1.0f / DMODEL) - mu * mu;
        red[8] = mu;
        red[9] = rsqrtf(var + 1e-5f);
    }
    __syncthreads();
    float mu = red[8], rs = red[9];
#pragma unroll
    for (int i = 0; i < 3; ++i) {
        int c = tid + i * 256;
        float o = (v[i] - mu) * rs * w[c] + b[c];
        if (BF16OUT) ((__hip_bfloat16*)outp)[(size_t)row * DMODEL + c] = __float2bfloat16(o);
        else         ((float*)outp)[(size_t)row * DMODEL + c] = o;
    }
}

// ---------------- Weight transpose+convert: W[K,N] fp32 -> Wt[N,K] bf16 ----------------
__global__ __launch_bounds__(256) void transpose_w(
    const float* __restrict__ W, __hip_bfloat16* __restrict__ Wt, int K, int N)
{
    __shared__ float T[64][65];
    int tid = threadIdx.x;
    int tx = tid & 63, ty = tid >> 6;
    int n0 = blockIdx.x * 64, k0 = blockIdx.y * 64;
#pragma unroll
    for (int i = 0; i < 16; ++i)
        T[ty + 4 * i][tx] = W[(size_t)(k0 + ty + 4 * i) * N + n0 + tx];
    __syncthreads();
#pragma unroll
    for (int i = 0; i < 16; ++i)
        Wt[(size_t)(n0 + ty + 4 * i) * K + k0 + tx] = __float2bfloat16(T[tx][ty + 4 * i]);
}

// ---------------- bf16 MFMA GEMM: C = act(A@Bt^T + bias) + resid ----------------
// A [M,K] bf16 row-major; Bt [N,K] bf16 row-major (pre-transposed weight).
// 128x128 tile, BK=64, 4 waves each 64x64, 16x16x32 MFMA.
// Fragment-major LDS: chunk c=(half<<3)|(t<<2)|f holds one wave-fragment in lane order.
template<int HAS_BIAS, int ACT_GELU, int HAS_RES, int OUT_BF16>
__global__ __launch_bounds__(256) void gemm_bf16(
    const __hip_bfloat16* __restrict__ A, const __hip_bfloat16* __restrict__ Bt,
    const float* __restrict__ bias, const float* __restrict__ resid,
    void* __restrict__ Cout, int M, int N, int K)
{
    __shared__ __hip_bfloat16 Afr[16 * 512];   // 16 chunks x 1KB
    __shared__ __hip_bfloat16 Bfr[16 * 512];

    int tid = threadIdx.x;
    int lane = tid & 63;
    int w = tid >> 6;
    int wm = w >> 1, wn = w & 1;
    int m0 = blockIdx.y * 128;
    int n0 = blockIdx.x * 128;
    int l15 = lane & 15;
    int quad = lane >> 4;

    f32x4 acc[4][4];
#pragma unroll
    for (int i = 0; i < 4; ++i)
#pragma unroll
        for (int j = 0; j < 4; ++j) {
            f32x4 z = {0.f, 0.f, 0.f, 0.f};
            acc[i][j] = z;
        }

    // per-lane source layout for chunk c: row (in tile) = (c>>3)*64 + (c&3)*16 + l15,
    // k offset = ((c>>2)&1)*32 + quad*8
    for (int k0 = 0; k0 < K; k0 += 64) {
#pragma unroll
        for (int i = 0; i < 4; ++i) {
            int c = w * 4 + i;
            int row = ((c >> 3) << 6) + ((c & 3) << 4) + l15;
            int kc  = k0 + (((c >> 2) & 1) << 5) + (quad << 3);
            gld16(A  + (size_t)(m0 + row) * K + kc, &Afr[c * 512]);
            gld16(Bt + (size_t)(n0 + row) * K + kc, &Bfr[c * 512]);
        }
        __syncthreads();   // drains vmcnt before barrier -> tiles visible
#pragma unroll
        for (int t = 0; t < 2; ++t) {
            bf16x8 a[4], b[4];
#pragma unroll
            for (int f = 0; f < 4; ++f) {
                a[f] = *(const bf16x8*)&Afr[(wm * 8 + t * 4 + f) * 512 + lane * 8];
                b[f] = *(const bf16x8*)&Bfr[(wn * 8 + t * 4 + f) * 512 + lane * 8];
            }
#pragma unroll
            for (int i = 0; i < 4; ++i)
#pragma unroll
                for (int j = 0; j < 4; ++j)
                    acc[i][j] = __builtin_amdgcn_mfma_f32_16x16x32_bf16(
                        a[i], b[j], acc[i][j], 0, 0, 0);
        }
        __syncthreads();   // all reads done before next stage overwrites
    }

    // epilogue: D row = quad*4+r, col = l15 within each 16x16 frag
#pragma unroll
    for (int i = 0; i < 4; ++i) {
#pragma unroll
        for (int j = 0; j < 4; ++j) {
            int col = n0 + wn * 64 + j * 16 + l15;
            float bv = HAS_BIAS ? bias[col] : 0.f;
#pragma unroll
            for (int r = 0; r < 4; ++r) {
                int row = m0 + wm * 64 + i * 16 + quad * 4 + r;
                float val = acc[i][j][r] + bv;
                if (ACT_GELU) val = 0.5f * val * (1.0f + erff(val * 0.70710678118f));
                if (HAS_RES)  val += resid[(size_t)row * N + col];
                if (OUT_BF16) ((__hip_bfloat16*)Cout)[(size_t)row * N + col] = __float2bfloat16(val);
                else          ((float*)Cout)[(size_t)row * N + col] = val;
            }
        }
    }
}

// ---------------- Flash attention: bf16 qkv in, bf16 out ----------------
#define PADF 68
__global__ __launch_bounds__(256) void fattn_kernel(
    const __hip_bfloat16* __restrict__ qkv, __hip_bfloat16* __restrict__ out)
{
    __shared__ float Qs[64][PADF];
    __shared__ float Ks[64][PADF];   // reused as P after S phase
    __shared__ float Vs[64][PADF];

    int qt = blockIdx.x, h = blockIdx.y, b = blockIdx.z;
    int tid = threadIdx.x;
    int tx = tid & 15;
    int ty = tid >> 4;
    int lr = tid >> 3;     // load row 0..31
    int lc = tid & 7;      // 16B chunk (8 bf16)

    const __hip_bfloat16* Qbase = qkv + (size_t)(b * SEQ + qt * 64) * QKVN + h * DHEAD;
    const __hip_bfloat16* Kbase = qkv + (size_t)(b * SEQ) * QKVN + DMODEL + h * DHEAD;
    const __hip_bfloat16* Vbase = Kbase + DMODEL;

#pragma unroll
    for (int p = 0; p < 2; ++p) {
        int r = lr + 32 * p;
        uint4 raw = *(const uint4*)(Qbase + (size_t)r * QKVN + lc * 8);
        float f[8]; unpack8(raw, f);
#pragma unroll
        for (int k = 0; k < 8; ++k) Qs[r][lc * 8 + k] = f[k] * 0.125f;
    }

    float m_i[4], l_i[4], o[4][4];
#pragma unroll
    for (int i = 0; i < 4; ++i) {
        m_i[i] = -1e30f; l_i[i] = 0.f;
#pragma unroll
        for (int j = 0; j < 4; ++j) o[i][j] = 0.f;
    }

    for (int kt = 0; kt < 16; ++kt) {
        uint4 kraw[2], vraw[2];
#pragma unroll
        for (int p = 0; p < 2; ++p) {
            int r = kt * 64 + lr + 32 * p;
            kraw[p] = *(const uint4*)(Kbase + (size_t)r * QKVN + lc * 8);
            vraw[p] = *(const uint4*)(Vbase + (size_t)r * QKVN + lc * 8);
        }
        __syncthreads();   // prior PV reads complete
#pragma unroll
        for (int p = 0; p < 2; ++p) {
            int r = lr + 32 * p;
            float f[8];
            unpack8(kraw[p], f);
#pragma unroll
            for (int k = 0; k < 8; ++k) Ks[r][lc * 8 + k] = f[k];
            unpack8(vraw[p], f);
#pragma unroll
            for (int k = 0; k < 8; ++k) Vs[r][lc * 8 + k] = f[k];
        }
        __syncthreads();   // tiles ready

        // S = Q @ K^T ; thread: 4 q-rows (ty*4+i) x 4 k-cols (tx+16*j)
        float s[4][4] = {};
#pragma unroll
        for (int d0 = 0; d0 < 64; d0 += 4) {
            float4 a4[4], b4[4];
#pragma unroll
            for (int i = 0; i < 4; ++i) a4[i] = *(const float4*)&Qs[ty * 4 + i][d0];
#pragma unroll
            for (int j = 0; j < 4; ++j) b4[j] = *(const float4*)&Ks[tx + 16 * j][d0];
#pragma unroll
            for (int i = 0; i < 4; ++i)
#pragma unroll
                for (int j = 0; j < 4; ++j)
                    s[i][j] += a4[i].x * b4[j].x + a4[i].y * b4[j].y
                             + a4[i].z * b4[j].z + a4[i].w * b4[j].w;
        }

        // online softmax (row stats across the 16-lane tx group)
#pragma unroll
        for (int i = 0; i < 4; ++i) {
            float rm = fmaxf(fmaxf(s[i][0], s[i][1]), fmaxf(s[i][2], s[i][3]));
#pragma unroll
            for (int off = 8; off > 0; off >>= 1) rm = fmaxf(rm, __shfl_xor(rm, off));
            float mnew = fmaxf(m_i[i], rm);
            float alpha = __expf(m_i[i] - mnew);
            float sum = 0.f;
#pragma unroll
            for (int j = 0; j < 4; ++j) {
                s[i][j] = __expf(s[i][j] - mnew);
                sum += s[i][j];
            }
#pragma unroll
            for (int off = 8; off > 0; off >>= 1) sum += __shfl_xor(sum, off);
            l_i[i] = l_i[i] * alpha + sum;
            m_i[i] = mnew;
#pragma unroll
            for (int j = 0; j < 4; ++j) o[i][j] *= alpha;
        }

        __syncthreads();   // S reads of Ks done; overwrite with P
#pragma unroll
        for (int i = 0; i < 4; ++i)
#pragma unroll
            for (int j = 0; j < 4; ++j)
                Ks[ty * 4 + i][tx + 16 * j] = s[i][j];
        __syncthreads();   // P ready

        // O += P @ V
#pragma unroll
        for (int k0 = 0; k0 < 64; k0 += 4) {
            float p4[4][4], v4[4][4];
#pragma unroll
            for (int i = 0; i < 4; ++i)
                *(float4*)p4[i] = *(const float4*)&Ks[ty * 4 + i][k0];
#pragma unroll
            for (int c = 0; c < 4; ++c)
                *(float4*)v4[c] = *(const float4*)&Vs[k0 + c][tx * 4];
#pragma unroll
            for (int i = 0; i < 4; ++i)
#pragma unroll
                for (int j = 0; j < 4; ++j)
                    o[i][j] += p4[i][0] * v4[0][j] + p4[i][1] * v4[1][j]
                             + p4[i][2] * v4[2][j] + p4[i][3] * v4[3][j];
        }
    }

#pragma unroll
    for (int i = 0; i < 4; ++i) {
        float inv = 1.0f / l_i[i];
        int row = b * SEQ + qt * 64 + ty * 4 + i;
        __hip_bfloat16* op = out + (size_t)row * DMODEL + h * DHEAD + tx * 4;
#pragma unroll
        for (int j = 0; j < 4; ++j) op[j] = __float2bfloat16(o[i][j] * inv);
    }
}

// ---------------- Launcher ----------------
extern "C" void kernel_launch(void* const* d_in, const int* in_sizes, int n_in,
                              void* d_out, int out_size, void* d_ws, size_t ws_size,
                              hipStream_t stream)
{
    const float* x      = (const float*)d_in[0];
    const float* ln1_w  = (const float*)d_in[1];
    const float* ln1_b  = (const float*)d_in[2];
    const float* w_qkv  = (const float*)d_in[3];
    const float* w_o    = (const float*)d_in[4];
    const float* b_o    = (const float*)d_in[5];
    const float* ln2_w  = (const float*)d_in[6];
    const float* ln2_b  = (const float*)d_in[7];
    const float* w1     = (const float*)d_in[8];
    const float* b1     = (const float*)d_in[9];
    const float* w2     = (const float*)d_in[10];
    const float* b2     = (const float*)d_in[11];
    const float* lnf_w  = (const float*)d_in[12];
    const float* lnf_b  = (const float*)d_in[13];

    char* p = (char*)d_ws;
    float* xbuf = (float*)p;                 p += (size_t)MROWS * DMODEL * 4;
    __hip_bfloat16* qkv  = (__hip_bfloat16*)p; p += (size_t)MROWS * QKVN * 2;
    __hip_bfloat16* hbuf = (__hip_bfloat16*)p; p += (size_t)MROWS * DMODEL * 2;
    __hip_bfloat16* ffn1 = (__hip_bfloat16*)p; p += (size_t)MROWS * DFF * 2;
    __hip_bfloat16* wq_t = (__hip_bfloat16*)p; p += (size_t)QKVN * DMODEL * 2;
    __hip_bfloat16* wo_t = (__hip_bfloat16*)p; p += (size_t)DMODEL * DMODEL * 2;
    __hip_bfloat16* w1_t = (__hip_bfloat16*)p; p += (size_t)DFF * DMODEL * 2;
    __hip_bfloat16* w2_t = (__hip_bfloat16*)p; p += (size_t)DMODEL * DFF * 2;

    hipMemcpyAsync(xbuf, x, (size_t)MROWS * DMODEL * sizeof(float),
                   hipMemcpyDeviceToDevice, stream);

    for (int l = 0; l < DEPTH; ++l) {
        const float* l1w = ln1_w + (size_t)l * DMODEL;
        const float* l1b = ln1_b + (size_t)l * DMODEL;
        const float* wq  = w_qkv + (size_t)l * DMODEL * QKVN;
        const float* wo  = w_o   + (size_t)l * DMODEL * DMODEL;
        const float* bo  = b_o   + (size_t)l * DMODEL;
        const float* l2w = ln2_w + (size_t)l * DMODEL;
        const float* l2b = ln2_b + (size_t)l * DMODEL;
        const float* W1  = w1    + (size_t)l * DMODEL * DFF;
        const float* B1  = b1    + (size_t)l * DFF;
        const float* W2  = w2    + (size_t)l * DFF * DMODEL;
        const float* B2  = b2    + (size_t)l * DMODEL;

        // per-layer weight transpose+convert (stream-ordered before use)
        transpose_w<<<dim3(QKVN / 64, DMODEL / 64), 256, 0, stream>>>(wq, wq_t, DMODEL, QKVN);
        transpose_w<<<dim3(DMODEL / 64, DMODEL / 64), 256, 0, stream>>>(wo, wo_t, DMODEL, DMODEL);
        transpose_w<<<dim3(DFF / 64, DMODEL / 64), 256, 0, stream>>>(W1, w1_t, DMODEL, DFF);
        transpose_w<<<dim3(DMODEL / 64, DFF / 64), 256, 0, stream>>>(W2, w2_t, DFF, DMODEL);

        ln_kernel<1><<<MROWS, 256, 0, stream>>>(xbuf, hbuf, l1w, l1b);
        gemm_bf16<0,0,0,1><<<dim3(QKVN / 128, MROWS / 128), 256, 0, stream>>>(
            hbuf, wq_t, nullptr, nullptr, qkv, MROWS, QKVN, DMODEL);
        fattn_kernel<<<dim3(SEQ / 64, NHEAD, BATCH), 256, 0, stream>>>(qkv, hbuf);
        gemm_bf16<1,0,1,0><<<dim3(DMODEL / 128, MROWS / 128), 256, 0, stream>>>(
            hbuf, wo_t, bo, xbuf, xbuf, MROWS, DMODEL, DMODEL);
        ln_kernel<1><<<MROWS, 256, 0, stream>>>(xbuf, hbuf, l2w, l2b);
        gemm_bf16<1,1,0,1><<<dim3(DFF / 128, MROWS / 128), 256, 0, stream>>>(
            hbuf, w1_t, B1, nullptr, ffn1, MROWS, DFF, DMODEL);
        gemm_bf16<1,0,1,0><<<dim3(DMODEL / 128, MROWS / 128), 256, 0, stream>>>(
            ffn1, w2_t, B2, xbuf, xbuf, MROWS, DMODEL, DFF);
    }

    ln_kernel<0><<<MROWS, 256, 0, stream>>>(xbuf, (float*)d_out, lnf_w, lnf_b);
}

// Round 4
// 4714.634 us; speedup vs baseline: 21.3914x; 2.7702x over previous
//
#include <hip/hip_runtime.h>
#include <hip/hip_bf16.h>
#include <math.h>

#define BATCH 8
#define SEQ   1024
#define DMODEL 768
#define DEPTH 12
#define NHEAD 12
#define DHEAD 64
#define DFF   3072
#define MROWS (BATCH*SEQ)        // 8192
#define QKVN  (3*DMODEL)         // 2304

typedef __attribute__((ext_vector_type(8))) short bf16x8;
typedef __attribute__((ext_vector_type(4))) float f32x4;

__device__ __forceinline__ void gld16(const void* g, void* l) {
    __builtin_amdgcn_global_load_lds(
        (const __attribute__((address_space(1))) void*)g,
        (__attribute__((address_space(3))) void*)l, 16, 0, 0);
}
__device__ __forceinline__ unsigned short bf16b(float f) {
    __hip_bfloat16 hb = __float2bfloat16(f);
    return *(unsigned short*)&hb;
}

// ---------------- LayerNorm: fp32 in, bf16 or fp32 out ----------------
template<int BF16OUT>
__global__ __launch_bounds__(256) void ln_kernel(
    const float* __restrict__ in, void* __restrict__ outp,
    const float* __restrict__ w, const float* __restrict__ b)
{
    int row = blockIdx.x;
    const float* x = in + (size_t)row * DMODEL;
    int tid = threadIdx.x;

    float v[3];
    float lsum = 0.f, lsq = 0.f;
#pragma unroll
    for (int i = 0; i < 3; ++i) {
        v[i] = x[tid + i * 256];
        lsum += v[i];
        lsq  += v[i] * v[i];
    }
#pragma unroll
    for (int off = 32; off > 0; off >>= 1) {
        lsum += __shfl_down(lsum, off);
        lsq  += __shfl_down(lsq,  off);
    }
    __shared__ float red[10];
    int wave = tid >> 6, lane = tid & 63;
    if (lane == 0) { red[wave] = lsum; red[wave + 4] = lsq; }
    __syncthreads();
    if (tid == 0) {
        float s = red[0] + red[1] + red[2] + red[3];
        float q = red[4] + red[5] + red[6] + red[7];
        float mu = s * (1.0f / DMODEL);
        float var = q * (1.0f / DMODEL) - mu * mu;
        red[8] = mu;
        red[9] = rsqrtf(var + 1e-5f);
    }
    __syncthreads();
    float mu = red[8], rs = red[9];
#pragma unroll
    for (int i = 0; i < 3; ++i) {
        int c = tid + i * 256;
        float o = (v[i] - mu) * rs * w[c] + b[c];
        if (BF16OUT) ((__hip_bfloat16*)outp)[(size_t)row * DMODEL + c] = __float2bfloat16(o);
        else         ((float*)outp)[(size_t)row * DMODEL + c] = o;
    }
}

// ---------------- Weight transpose+convert: W[K,N] fp32 -> Wt[N,K] bf16 ----------------
__global__ __launch_bounds__(256) void transpose_w(
    const float* __restrict__ W, __hip_bfloat16* __restrict__ Wt, int K, int N)
{
    __shared__ float T[64][65];
    int tid = threadIdx.x;
    int tx = tid & 63, ty = tid >> 6;
    int n0 = blockIdx.x * 64, k0 = blockIdx.y * 64;
#pragma unroll
    for (int i = 0; i < 16; ++i)
        T[ty + 4 * i][tx] = W[(size_t)(k0 + ty + 4 * i) * N + n0 + tx];
    __syncthreads();
#pragma unroll
    for (int i = 0; i < 16; ++i)
        Wt[(size_t)(n0 + ty + 4 * i) * K + k0 + tx] = __float2bfloat16(T[tx][ty + 4 * i]);
}

// ---------------- V transpose: qkv V-part [seq][h*64+d] -> vt [b][h][d][seq] ----------------
__global__ __launch_bounds__(256) void transpose_v(
    const __hip_bfloat16* __restrict__ qkv, __hip_bfloat16* __restrict__ vt)
{
    __shared__ unsigned int T[64 * 33];   // row stride 33 dwords = 66 bf16
    int tid = threadIdx.x;
    int s0 = blockIdx.x * 64, h = blockIdx.y, b = blockIdx.z;
    const __hip_bfloat16* src = qkv + ((size_t)(b * SEQ + s0)) * QKVN + 2 * DMODEL + h * DHEAD;
#pragma unroll
    for (int p = 0; p < 2; ++p) {
        int row = (tid >> 3) + 32 * p;
        int c8 = tid & 7;
        uint4 v = *(const uint4*)(src + (size_t)row * QKVN + c8 * 8);
        unsigned int* dst = &T[row * 33 + c8 * 4];
        dst[0] = v.x; dst[1] = v.y; dst[2] = v.z; dst[3] = v.w;
    }
    __syncthreads();
    __hip_bfloat16* ob = vt + ((size_t)(b * NHEAD + h)) * DHEAD * SEQ;
    const unsigned short* Ts = (const unsigned short*)T;
#pragma unroll
    for (int p = 0; p < 2; ++p) {
        int d = (tid >> 3) + 32 * p;
        int sb = (tid & 7) * 8;
        unsigned int wds[4];
#pragma unroll
        for (int j = 0; j < 4; ++j) {
            unsigned int lo = Ts[(size_t)(sb + 2 * j) * 66 + d];
            unsigned int hi = Ts[(size_t)(sb + 2 * j + 1) * 66 + d];
            wds[j] = lo | (hi << 16);
        }
        *(uint4*)(ob + (size_t)d * SEQ + s0 + sb) = *(const uint4*)wds;
    }
}

// ---------------- bf16 MFMA GEMM (unchanged from round 3) ----------------
template<int HAS_BIAS, int ACT_GELU, int HAS_RES, int OUT_BF16>
__global__ __launch_bounds__(256) void gemm_bf16(
    const __hip_bfloat16* __restrict__ A, const __hip_bfloat16* __restrict__ Bt,
    const float* __restrict__ bias, const float* __restrict__ resid,
    void* __restrict__ Cout, int M, int N, int K)
{
    __shared__ __hip_bfloat16 Afr[16 * 512];
    __shared__ __hip_bfloat16 Bfr[16 * 512];

    int tid = threadIdx.x;
    int lane = tid & 63;
    int w = tid >> 6;
    int wm = w >> 1, wn = w & 1;
    int m0 = blockIdx.y * 128;
    int n0 = blockIdx.x * 128;
    int l15 = lane & 15;
    int quad = lane >> 4;

    f32x4 acc[4][4];
#pragma unroll
    for (int i = 0; i < 4; ++i)
#pragma unroll
        for (int j = 0; j < 4; ++j) {
            f32x4 z = {0.f, 0.f, 0.f, 0.f};
            acc[i][j] = z;
        }

    for (int k0 = 0; k0 < K; k0 += 64) {
#pragma unroll
        for (int i = 0; i < 4; ++i) {
            int c = w * 4 + i;
            int row = ((c >> 3) << 6) + ((c & 3) << 4) + l15;
            int kc  = k0 + (((c >> 2) & 1) << 5) + (quad << 3);
            gld16(A  + (size_t)(m0 + row) * K + kc, &Afr[c * 512]);
            gld16(Bt + (size_t)(n0 + row) * K + kc, &Bfr[c * 512]);
        }
        __syncthreads();
#pragma unroll
        for (int t = 0; t < 2; ++t) {
            bf16x8 a[4], b[4];
#pragma unroll
            for (int f = 0; f < 4; ++f) {
                a[f] = *(const bf16x8*)&Afr[(wm * 8 + t * 4 + f) * 512 + lane * 8];
                b[f] = *(const bf16x8*)&Bfr[(wn * 8 + t * 4 + f) * 512 + lane * 8];
            }
#pragma unroll
            for (int i = 0; i < 4; ++i)
#pragma unroll
                for (int j = 0; j < 4; ++j)
                    acc[i][j] = __builtin_amdgcn_mfma_f32_16x16x32_bf16(
                        a[i], b[j], acc[i][j], 0, 0, 0);
        }
        __syncthreads();
    }

#pragma unroll
    for (int i = 0; i < 4; ++i) {
#pragma unroll
        for (int j = 0; j < 4; ++j) {
            int col = n0 + wn * 64 + j * 16 + l15;
            float bv = HAS_BIAS ? bias[col] : 0.f;
#pragma unroll
            for (int r = 0; r < 4; ++r) {
                int row = m0 + wm * 64 + i * 16 + quad * 4 + r;
                float val = acc[i][j][r] + bv;
                if (ACT_GELU) val = 0.5f * val * (1.0f + erff(val * 0.70710678118f));
                if (HAS_RES)  val += resid[(size_t)row * N + col];
                if (OUT_BF16) ((__hip_bfloat16*)Cout)[(size_t)row * N + col] = __float2bfloat16(val);
                else          ((float*)Cout)[(size_t)row * N + col] = val;
            }
        }
    }
}

// ---------------- MFMA flash attention ----------------
// Block: 256 thr / 4 waves; 128 q-rows per block (32 per wave); ktile = 64 kpos.
// S^T = K.Q^T (C-layout: col=q=l15 -> softmax state lane-indexed, quad-uniform).
// P C-rows are kpos-contiguous -> b64 LDS writes; PV: O^T = Vt.P (A=Vt frag, B=P frag).
__global__ __launch_bounds__(256) void fattn_mfma(
    const __hip_bfloat16* __restrict__ qkv,
    const __hip_bfloat16* __restrict__ vt,
    __hip_bfloat16* __restrict__ out)
{
    __shared__ __align__(16) char lds[8192 + 8192 + 4 * 4608];   // Kfr, Vfr, P/Qst
    char* Kfr = lds;
    char* Vfr = lds + 8192;
    char* Pbase = lds + 16384;

    int tid = threadIdx.x;
    int lane = tid & 63;
    int w = tid >> 6;
    int l15 = lane & 15, quad = lane >> 4;
    int qt = blockIdx.x, h = blockIdx.y, b = blockIdx.z;

    unsigned short* Pw = (unsigned short*)(Pbase + w * 4608);   // [32 q][72] bf16

    const int q0 = qt * 128 + w * 32;   // seq offset of this wave's 32 q-rows
    const __hip_bfloat16* Qp = qkv + ((size_t)(b * SEQ + q0)) * QKVN + h * DHEAD;
    const __hip_bfloat16* Kp = qkv + ((size_t)(b * SEQ)) * QKVN + DMODEL + h * DHEAD;
    const __hip_bfloat16* Vp = vt + ((size_t)(b * NHEAD + h)) * DHEAD * SEQ;

    // stage Q frags through P region (chunk c = w*4 + qs*2 + kh)
#pragma unroll
    for (int i = 0; i < 4; ++i) {
        int qs = i >> 1, kh = i & 1;
        gld16(Qp + (size_t)(qs * 16 + l15) * QKVN + kh * 32 + quad * 8,
              Pbase + (w * 4 + i) * 1024);
    }
    __syncthreads();
    bf16x8 qf[2][2];
#pragma unroll
    for (int i = 0; i < 4; ++i)
        qf[i >> 1][i & 1] = *(const bf16x8*)(Pbase + (w * 4 + i) * 1024 + lane * 16);
    // no barrier needed: first loop barrier orders Q reads before any P write

    float m_st[2] = {-1e30f, -1e30f};
    float l_st[2] = {0.f, 0.f};
    f32x4 accO[2][4];
#pragma unroll
    for (int qs = 0; qs < 2; ++qs)
#pragma unroll
        for (int ds = 0; ds < 4; ++ds) {
            f32x4 z = {0.f, 0.f, 0.f, 0.f};
            accO[qs][ds] = z;
        }

    for (int kt = 0; kt < 16; ++kt) {
        __syncthreads();   // prior iter's Kfr/Vfr reads complete
#pragma unroll
        for (int i = 0; i < 4; ++i) {
            int c = w * 4 + i;
            if (c < 8) {   // K chunk: ks = c>>1, kh = c&1
                gld16(Kp + (size_t)(kt * 64 + ((c >> 1) << 4) + l15) * QKVN
                         + ((c & 1) << 5) + quad * 8,
                      Kfr + c * 1024);
            } else {       // Vt chunk: ds = (c-8)>>1, kh = (c-8)&1
                int c2 = c - 8;
                gld16(Vp + (size_t)(((c2 >> 1) << 4) + l15) * SEQ
                         + kt * 64 + ((c2 & 1) << 5) + quad * 8,
                      Vfr + c2 * 1024);
            }
        }
        __syncthreads();   // vmcnt drained: tiles visible

        // S^T: sA[qs][ks], D row = kpos = ks*16+quad*4+r, col = q = l15
        f32x4 sA[2][4];
#pragma unroll
        for (int qs = 0; qs < 2; ++qs)
#pragma unroll
            for (int ks = 0; ks < 4; ++ks) {
                f32x4 z = {0.f, 0.f, 0.f, 0.f};
                sA[qs][ks] = z;
            }
#pragma unroll
        for (int ks = 0; ks < 4; ++ks)
#pragma unroll
            for (int kh = 0; kh < 2; ++kh) {
                bf16x8 kf = *(const bf16x8*)(Kfr + (ks * 2 + kh) * 1024 + lane * 16);
                sA[0][ks] = __builtin_amdgcn_mfma_f32_16x16x32_bf16(kf, qf[0][kh], sA[0][ks], 0, 0, 0);
                sA[1][ks] = __builtin_amdgcn_mfma_f32_16x16x32_bf16(kf, qf[1][kh], sA[1][ks], 0, 0, 0);
            }

        // online softmax per qs (state indexed by q = l15, uniform across quads)
#pragma unroll
        for (int qs = 0; qs < 2; ++qs) {
            float rm = sA[qs][0][0];
#pragma unroll
            for (int ks = 0; ks < 4; ++ks)
#pragma unroll
                for (int r = 0; r < 4; ++r) rm = fmaxf(rm, sA[qs][ks][r]);
            rm = fmaxf(rm, __shfl_xor(rm, 16));
            rm = fmaxf(rm, __shfl_xor(rm, 32));
            float mnew = fmaxf(m_st[qs], rm * 0.125f);
            float alpha = __expf(m_st[qs] - mnew);
            m_st[qs] = mnew;
            float sum = 0.f;
            unsigned short pb[4][4];
#pragma unroll
            for (int ks = 0; ks < 4; ++ks)
#pragma unroll
                for (int r = 0; r < 4; ++r) {
                    float p = __expf(sA[qs][ks][r] * 0.125f - mnew);
                    sum += p;
                    pb[ks][r] = bf16b(p);
                }
            sum += __shfl_xor(sum, 16);
            sum += __shfl_xor(sum, 32);
            l_st[qs] = l_st[qs] * alpha + sum;
#pragma unroll
            for (int ds = 0; ds < 4; ++ds) accO[qs][ds] *= alpha;
            // P write: rows kpos contiguous -> b64 per ks
#pragma unroll
            for (int ks = 0; ks < 4; ++ks) {
                unsigned int lo = pb[ks][0] | ((unsigned int)pb[ks][1] << 16);
                unsigned int hi = pb[ks][2] | ((unsigned int)pb[ks][3] << 16);
                unsigned int* dst = (unsigned int*)(Pw + (qs * 16 + l15) * 72 + ks * 16 + quad * 4);
                dst[0] = lo; dst[1] = hi;
            }
        }

        // PV: O^T[d][q] += Vt . P   (same-wave P, no barrier)
#pragma unroll
        for (int kh = 0; kh < 2; ++kh) {
            bf16x8 vf[4];
#pragma unroll
            for (int ds = 0; ds < 4; ++ds)
                vf[ds] = *(const bf16x8*)(Vfr + (ds * 2 + kh) * 1024 + lane * 16);
#pragma unroll
            for (int qs = 0; qs < 2; ++qs) {
                bf16x8 pf = *(const bf16x8*)(Pw + (qs * 16 + l15) * 72 + kh * 32 + quad * 8);
#pragma unroll
                for (int ds = 0; ds < 4; ++ds)
                    accO[qs][ds] = __builtin_amdgcn_mfma_f32_16x16x32_bf16(
                        vf[ds], pf, accO[qs][ds], 0, 0, 0);
            }
        }
    }

    // epilogue: normalize, transpose O^T -> natural through Pw, coalesced store
#pragma unroll
    for (int qs = 0; qs < 2; ++qs) {
        float inv = 1.0f / l_st[qs];
#pragma unroll
        for (int ds = 0; ds < 4; ++ds) {
            unsigned short u[4];
#pragma unroll
            for (int r = 0; r < 4; ++r) u[r] = bf16b(accO[qs][ds][r] * inv);
            unsigned int lo = u[0] | ((unsigned int)u[1] << 16);
            unsigned int hi = u[2] | ((unsigned int)u[3] << 16);
            unsigned int* dst = (unsigned int*)(Pw + (qs * 16 + l15) * 72 + ds * 16 + quad * 4);
            dst[0] = lo; dst[1] = hi;
        }
    }
    __hip_bfloat16* ob = out + ((size_t)(b * SEQ + q0)) * DMODEL + h * DHEAD;
#pragma unroll
    for (int i = 0; i < 4; ++i) {
        int row = i * 8 + (lane >> 3);
        uint4 v = *(const uint4*)(Pw + row * 72 + (lane & 7) * 8);
        *(uint4*)(ob + (size_t)row * DMODEL + (lane & 7) * 8) = v;
    }
}

// ---------------- Launcher ----------------
extern "C" void kernel_launch(void* const* d_in, const int* in_sizes, int n_in,
                              void* d_out, int out_size, void* d_ws, size_t ws_size,
                              hipStream_t stream)
{
    const float* x      = (const float*)d_in[0];
    const float* ln1_w  = (const float*)d_in[1];
    const float* ln1_b  = (const float*)d_in[2];
    const float* w_qkv  = (const float*)d_in[3];
    const float* w_o    = (const float*)d_in[4];
    const float* b_o    = (const float*)d_in[5];
    const float* ln2_w  = (const float*)d_in[6];
    const float* ln2_b  = (const float*)d_in[7];
    const float* w1     = (const float*)d_in[8];
    const float* b1     = (const float*)d_in[9];
    const float* w2     = (const float*)d_in[10];
    const float* b2     = (const float*)d_in[11];
    const float* lnf_w  = (const float*)d_in[12];
    const float* lnf_b  = (const float*)d_in[13];

    char* p = (char*)d_ws;
    float* xbuf = (float*)p;                   p += (size_t)MROWS * DMODEL * 4;
    __hip_bfloat16* qkv  = (__hip_bfloat16*)p; p += (size_t)MROWS * QKVN * 2;
    __hip_bfloat16* hbuf = (__hip_bfloat16*)p; p += (size_t)MROWS * DMODEL * 2;
    __hip_bfloat16* ffn1 = (__hip_bfloat16*)p; p += (size_t)MROWS * DFF * 2;
    __hip_bfloat16* wq_t = (__hip_bfloat16*)p; p += (size_t)QKVN * DMODEL * 2;
    __hip_bfloat16* wo_t = (__hip_bfloat16*)p; p += (size_t)DMODEL * DMODEL * 2;
    __hip_bfloat16* w1_t = (__hip_bfloat16*)p; p += (size_t)DFF * DMODEL * 2;
    __hip_bfloat16* w2_t = (__hip_bfloat16*)p; p += (size_t)DMODEL * DFF * 2;
    __hip_bfloat16* vtb  = (__hip_bfloat16*)p; p += (size_t)MROWS * DMODEL * 2;

    hipMemcpyAsync(xbuf, x, (size_t)MROWS * DMODEL * sizeof(float),
                   hipMemcpyDeviceToDevice, stream);

    for (int l = 0; l < DEPTH; ++l) {
        const float* l1w = ln1_w + (size_t)l * DMODEL;
        const float* l1b = ln1_b + (size_t)l * DMODEL;
        const float* wq  = w_qkv + (size_t)l * DMODEL * QKVN;
        const float* wo  = w_o   + (size_t)l * DMODEL * DMODEL;
        const float* bo  = b_o   + (size_t)l * DMODEL;
        const float* l2w = ln2_w + (size_t)l * DMODEL;
        const float* l2b = ln2_b + (size_t)l * DMODEL;
        const float* W1  = w1    + (size_t)l * DMODEL * DFF;
        const float* B1  = b1    + (size_t)l * DFF;
        const float* W2  = w2    + (size_t)l * DFF * DMODEL;
        const float* B2  = b2    + (size_t)l * DMODEL;

        transpose_w<<<dim3(QKVN / 64, DMODEL / 64), 256, 0, stream>>>(wq, wq_t, DMODEL, QKVN);
        transpose_w<<<dim3(DMODEL / 64, DMODEL / 64), 256, 0, stream>>>(wo, wo_t, DMODEL, DMODEL);
        transpose_w<<<dim3(DFF / 64, DMODEL / 64), 256, 0, stream>>>(W1, w1_t, DMODEL, DFF);
        transpose_w<<<dim3(DMODEL / 64, DFF / 64), 256, 0, stream>>>(W2, w2_t, DFF, DMODEL);

        ln_kernel<1><<<MROWS, 256, 0, stream>>>(xbuf, hbuf, l1w, l1b);
        gemm_bf16<0,0,0,1><<<dim3(QKVN / 128, MROWS / 128), 256, 0, stream>>>(
            hbuf, wq_t, nullptr, nullptr, qkv, MROWS, QKVN, DMODEL);
        transpose_v<<<dim3(SEQ / 64, NHEAD, BATCH), 256, 0, stream>>>(qkv, vtb);
        fattn_mfma<<<dim3(SEQ / 128, NHEAD, BATCH), 256, 0, stream>>>(qkv, vtb, hbuf);
        gemm_bf16<1,0,1,0><<<dim3(DMODEL / 128, MROWS / 128), 256, 0, stream>>>(
            hbuf, wo_t, bo, xbuf, xbuf, MROWS, DMODEL, DMODEL);
        ln_kernel<1><<<MROWS, 256, 0, stream>>>(xbuf, hbuf, l2w, l2b);
        gemm_bf16<1,1,0,1><<<dim3(DFF / 128, MROWS / 128), 256, 0, stream>>>(
            hbuf, w1_t, B1, nullptr, ffn1, MROWS, DFF, DMODEL);
        gemm_bf16<1,0,1,0><<<dim3(DMODEL / 128, MROWS / 128), 256, 0, stream>>>(
            ffn1, w2_t, B2, xbuf, xbuf, MROWS, DMODEL, DFF);
    }

    ln_kernel<0><<<MROWS, 256, 0, stream>>>(xbuf, (float*)d_out, lnf_w, lnf_b);
}